// Round 7
// baseline (2595.260 us; speedup 1.0000x reference)
//
#include <hip/hip_runtime.h>
#include <hip/hip_bf16.h>
#include <math.h>

typedef __bf16 bf16x8 __attribute__((ext_vector_type(8)));
typedef float floatx4 __attribute__((ext_vector_type(4)));
typedef unsigned int uint4v __attribute__((ext_vector_type(4)));

#define T_LEN 128

// ws layout: bf16 fragment-packed weights (unchanged from R5/R6)
#define WP_OFF   0
#define WP_SZ    (64*10*64*16)     // gates: 64 ct x 10 ki x 64 lanes x 16B = 655360
#define W1P_OFF  (WP_OFF + WP_SZ)
#define W1P_SZ   (8*8*64*16)       // 65536
#define W2P_OFF  (W1P_OFF + W1P_SZ)
#define W2P_SZ   (8*4*64*16)       // 32768
#define WZP_OFF  (W2P_OFF + W2P_SZ)
#define WZP_SZ   (4*4*64*16)       // 16384
#define WS_NEEDED ((size_t)(WZP_OFF + WZP_SZ))   // 770048 B
#define MLP_BYTES (W1P_SZ + W2P_SZ + WZP_SZ)     // 114688 B
#define MLP_ELEM  (MLP_BYTES / 2)                // 57344 bf16
#define U2_EOFF   (W1P_SZ / 2)                   // 32768 elem
#define WZ_EOFF   ((W1P_SZ + W2P_SZ) / 2)        // 49152 elem

// ---------------- prep: f32 weights -> bf16 B-fragment-linear in ws -------
__global__ void prep_kernel(const float* __restrict__ Wih, const float* __restrict__ Whh,
                            const float* __restrict__ W1,  const float* __restrict__ W2,
                            const float* __restrict__ Wz,  unsigned char* __restrict__ ws)
{
    int id = blockIdx.x * blockDim.x + threadIdx.x;
    __bf16* Wp  = (__bf16*)(ws + WP_OFF);
    __bf16* W1p = (__bf16*)(ws + W1P_OFF);
    __bf16* W2p = (__bf16*)(ws + W2P_OFF);
    __bf16* Wzp = (__bf16*)(ws + WZP_OFF);
    if (id < 40960) {                       // gates: 64 ct x 10 ki x 64 lanes
        int rem = id % 640, lane = rem % 64;
        int row = (id / 640) * 16 + (lane & 15);         // gate-output col
        int kb  = (rem / 64) * 32 + (lane >> 4) * 8;
        for (int j = 0; j < 8; ++j) {
            int k = kb + j;
            float v;
            if (k < 40)       v = Wih[row * 40 + k];
            else if (k < 296) v = Whh[row * 256 + (k - 40)];
            else              v = 0.0f;                   // K-pad 296..319
            Wp[(size_t)id * 8 + j] = (__bf16)v;
        }
    } else if (id < 45056) {                // W1: 8 ct x 8 ki
        int id2 = id - 40960;
        int rem = id2 % 512, lane = rem % 64;
        int row = (id2 / 512) * 16 + (lane & 15);
        int kb  = (rem / 64) * 32 + (lane >> 4) * 8;
        for (int j = 0; j < 8; ++j) W1p[(size_t)id2 * 8 + j] = (__bf16)W1[row * 256 + kb + j];
    } else if (id < 47104) {                // W2: 8 ct x 4 ki
        int id3 = id - 45056;
        int rem = id3 % 256, lane = rem % 64;
        int row = (id3 / 256) * 16 + (lane & 15);
        int kb  = (rem / 64) * 32 + (lane >> 4) * 8;
        for (int j = 0; j < 8; ++j) W2p[(size_t)id3 * 8 + j] = (__bf16)W2[row * 128 + kb + j];
    } else if (id < 48128) {                // Wz: 4 ct x 4 ki
        int id4 = id - 47104;
        int rem = id4 % 256, lane = rem % 64;
        int row = (id4 / 256) * 16 + (lane & 15);
        int kb  = (rem / 64) * 32 + (lane >> 4) * 8;
        for (int j = 0; j < 8; ++j) Wzp[(size_t)id4 * 8 + j] = (__bf16)Wz[row * 128 + kb + j];
    }
}

// ---------------- fast path: 64 blocks x 1024 threads, 16 rows/block ------
// VGPR budget at 1024 thr = 128/wave (4 waves/EU). Plan:
//   persistent gates frags ki=0..2 : 12 x bf16x8 = 48 VGPR
//   streamed   gates frags ki=3..9 : depth-2 rotation (sA,sB) = 32 VGPR in flight
//   acc 16 + A-frag 4 + state/bias/addr ~25  => ~125 total, no spill.
// MLP weights in LDS (112 KB). Zero scratch, zero global weight re-reads
// except the pipelined gates stream (L2-resident, throughput-bound).
__global__ __launch_bounds__(1024, 4) void seq_mfma(
    const float* __restrict__ A,   const float* __restrict__ eps,
    const float* __restrict__ z0,  const float* __restrict__ h0,
    const float* __restrict__ c0,
    const float* __restrict__ bih, const float* __restrict__ bhh,
    const float* __restrict__ b1,  const float* __restrict__ b2,
    const float* __restrict__ bz,
    const unsigned char* __restrict__ ws, float* __restrict__ out)
{
    const int tid  = threadIdx.x;
    const int wave = tid >> 6;
    const int lane = tid & 63;
    const int lrow = lane & 15;
    const int quad = lane >> 4;
    const int n0   = blockIdx.x * 16;

    __shared__ __align__(16) __bf16 xh[16][328];   // [a(8)|z(32)|h(256)|pad(24)]
    __shared__ __align__(16) __bf16 u1s[16][136];
    __shared__ __align__(16) __bf16 u2s[16][136];
    __shared__ __align__(16) float  zzs[16][68];
    __shared__ __align__(16) __bf16 mlpw[MLP_ELEM];  // W1P|W2P|WZP verbatim

    // ---- one-time: MLP weights -> LDS (coalesced 16B copies)
    {
        const uint4v* src = (const uint4v*)(ws + W1P_OFF);
        uint4v* dst = (uint4v*)mlpw;
        #pragma unroll
        for (int i = 0; i < MLP_BYTES / 16 / 1024; ++i)
            dst[i * 1024 + tid] = src[i * 1024 + tid];
    }

    // per-lane gates fragment base pointers
    const char* gbase[4];
    #pragma unroll
    for (int g = 0; g < 4; ++g)
        gbase[g] = (const char*)ws + WP_OFF + ((size_t)((g * 16 + wave) * 10) * 64 + lane) * 16;
#define LDG(ki, g) (*(const bf16x8*)(gbase[g] + (ki) * 1024))

    // persistent gates frags ki=0..2 (48 VGPR)
    bf16x8 wgp[3][4];
    #pragma unroll
    for (int ki = 0; ki < 3; ++ki)
        #pragma unroll
        for (int g = 0; g < 4; ++g)
            wgp[ki][g] = LDG(ki, g);

    const int unit = wave * 16 + lrow;
    float gb[4];
    #pragma unroll
    for (int g = 0; g < 4; ++g)
        gb[g] = bih[g * 256 + unit] + bhh[g * 256 + unit];
    float u1b = b1[(wave & 7) * 16 + lrow];
    float u2b = b2[(wave & 7) * 16 + lrow];
    float zzb = bz[(wave & 3) * 16 + lrow];

    float cst[4];
    {
        float cv = c0[unit];
        #pragma unroll
        for (int r = 0; r < 4; ++r) cst[r] = cv;
    }

    // init z/h/pad of xh
    for (int idx = tid; idx < 16 * 320; idx += 1024) {
        int r = idx / 320, col = 8 + idx % 320;
        float v;
        if (col < 40)       v = z0[col - 8];
        else if (col < 296) v = h0[col - 40];
        else                v = 0.0f;
        xh[r][col] = (__bf16)v;
    }

    // prefetch a(t=0)
    float a_cur = 0.0f;
    if (tid < 128)
        a_cur = A[((size_t)(n0 + (tid >> 3)) * T_LEN + 0) * 8 + (tid & 7)];

    for (int t = 0; t < T_LEN; ++t) {
        // ---- stage a_t from prefetch register
        if (tid < 128)
            xh[tid >> 3][tid & 7] = (__bf16)a_cur;
        __syncthreads();   // orders a-stage, prev z writes, init writes, mlpw copy

        // ---- early-issue prefetches (consumed stages later)
        float eps_cur = 0.0f;
        if (tid < 512)
            eps_cur = eps[((size_t)(n0 + (tid >> 5)) * T_LEN + t) * 32 + (tid & 31)];
        float a_nxt = 0.0f;
        if (t + 1 < T_LEN && tid < 128)
            a_nxt = A[((size_t)(n0 + (tid >> 3)) * T_LEN + (t + 1)) * 8 + (tid & 7)];

        // ---- gates: LDS A-frags; B = 3 persistent ki + pipelined stream ki=3..9
        floatx4 acc[4];
        #pragma unroll
        for (int g = 0; g < 4; ++g)
            acc[g] = (floatx4){gb[g], gb[g], gb[g], gb[g]};

        bf16x8 sA[4], sB[4];
        #pragma unroll
        for (int g = 0; g < 4; ++g) sA[g] = LDG(3, g);
        #pragma unroll
        for (int g = 0; g < 4; ++g) sB[g] = LDG(4, g);

        #pragma unroll
        for (int ki = 0; ki < 3; ++ki) {
            bf16x8 a = *(const bf16x8*)&xh[lrow][ki * 32 + quad * 8];
            #pragma unroll
            for (int g = 0; g < 4; ++g)
                acc[g] = __builtin_amdgcn_mfma_f32_16x16x32_bf16(a, wgp[ki][g], acc[g], 0, 0, 0);
        }

#define GSTEP(KI, CUR, RKI, REFILL) do {                                          \
        bf16x8 a = *(const bf16x8*)&xh[lrow][(KI) * 32 + quad * 8];               \
        acc[0] = __builtin_amdgcn_mfma_f32_16x16x32_bf16(a, CUR[0], acc[0],0,0,0);\
        acc[1] = __builtin_amdgcn_mfma_f32_16x16x32_bf16(a, CUR[1], acc[1],0,0,0);\
        acc[2] = __builtin_amdgcn_mfma_f32_16x16x32_bf16(a, CUR[2], acc[2],0,0,0);\
        acc[3] = __builtin_amdgcn_mfma_f32_16x16x32_bf16(a, CUR[3], acc[3],0,0,0);\
        if (REFILL) {                                                             \
            CUR[0] = LDG(RKI, 0); CUR[1] = LDG(RKI, 1);                           \
            CUR[2] = LDG(RKI, 2); CUR[3] = LDG(RKI, 3);                           \
        }                                                                         \
    } while (0)

        GSTEP(3, sA, 5, 1);
        GSTEP(4, sB, 6, 1);
        GSTEP(5, sA, 7, 1);
        GSTEP(6, sB, 8, 1);
        GSTEP(7, sA, 9, 1);
        GSTEP(8, sB, 0, 0);
        GSTEP(9, sA, 0, 0);
#undef GSTEP
        __syncthreads();   // xh (a,z,h) reads complete

        // ---- LSTM cell: acc[0..3] = i,f,g,o for (row=quad*4+r, col=unit)
        #pragma unroll
        for (int r = 0; r < 4; ++r) {
            float iv = 1.0f / (1.0f + expf(-acc[0][r]));
            float fv = 1.0f / (1.0f + expf(-acc[1][r]));
            float gv = tanhf(acc[2][r]);
            float ov = 1.0f / (1.0f + expf(-acc[3][r]));
            float cn = fv * cst[r] + iv * gv;
            cst[r] = cn;
            xh[quad * 4 + r][40 + unit] = (__bf16)(ov * tanhf(cn));
        }
        __syncthreads();

        // ---- u1 = relu(h @ W1^T + b1): waves 0..7, weights from LDS
        if (wave < 8) {
            floatx4 a1 = (floatx4){u1b, u1b, u1b, u1b};
            #pragma unroll
            for (int ki = 0; ki < 8; ++ki) {
                bf16x8 a = *(const bf16x8*)&xh[lrow][40 + ki * 32 + quad * 8];
                bf16x8 b = *(const bf16x8*)&mlpw[(((wave & 7) * 8 + ki) * 64 + lane) * 8];
                a1 = __builtin_amdgcn_mfma_f32_16x16x32_bf16(a, b, a1, 0, 0, 0);
            }
            #pragma unroll
            for (int r = 0; r < 4; ++r)
                u1s[quad * 4 + r][wave * 16 + lrow] = (__bf16)fmaxf(a1[r], 0.0f);
        }
        __syncthreads();

        // ---- u2 = relu(u1 @ W2^T + b2): waves 0..7
        if (wave < 8) {
            floatx4 a2 = (floatx4){u2b, u2b, u2b, u2b};
            #pragma unroll
            for (int ki = 0; ki < 4; ++ki) {
                bf16x8 a = *(const bf16x8*)&u1s[lrow][ki * 32 + quad * 8];
                bf16x8 b = *(const bf16x8*)&mlpw[U2_EOFF + (((wave & 7) * 4 + ki) * 64 + lane) * 8];
                a2 = __builtin_amdgcn_mfma_f32_16x16x32_bf16(a, b, a2, 0, 0, 0);
            }
            #pragma unroll
            for (int r = 0; r < 4; ++r)
                u2s[quad * 4 + r][wave * 16 + lrow] = (__bf16)fmaxf(a2[r], 0.0f);
        }
        __syncthreads();

        // ---- zz = u2 @ Wz^T + bz: waves 0..3
        if (wave < 4) {
            floatx4 a3 = (floatx4){zzb, zzb, zzb, zzb};
            #pragma unroll
            for (int ki = 0; ki < 4; ++ki) {
                bf16x8 a = *(const bf16x8*)&u2s[lrow][ki * 32 + quad * 8];
                bf16x8 b = *(const bf16x8*)&mlpw[WZ_EOFF + (((wave & 3) * 4 + ki) * 64 + lane) * 8];
                a3 = __builtin_amdgcn_mfma_f32_16x16x32_bf16(a, b, a3, 0, 0, 0);
            }
            #pragma unroll
            for (int r = 0; r < 4; ++r)
                zzs[quad * 4 + r][wave * 16 + lrow] = a3[r];
        }
        __syncthreads();

        // ---- z = loc + softplus(raw)*eps (prefetched); f32 out + bf16 feedback
        if (tid < 512) {
            int r = tid >> 5, c = tid & 31;
            float loc = zzs[r][c];
            float raw = zzs[r][c + 32];
            float sp  = (raw > 20.0f) ? raw : log1pf(expf(raw));
            float zv  = loc + sp * eps_cur;
            xh[r][8 + c] = (__bf16)zv;
            out[((size_t)(n0 + r) * T_LEN + t) * 32 + c] = zv;
        }
        a_cur = a_nxt;
        // z writes (cols 8..39) vs next a-stage (cols 0..7) disjoint;
        // next post-a-stage barrier orders z before gates reads.
    }
#undef LDG
}

// ---------------- fallback: proven R4 VALU kernel (f32 hard-coded) --------
struct SM {
    float zx[4][40]; float h[4][256]; float u1[4][128]; float u2[4][128]; float zz[4][64];
};

__global__ __launch_bounds__(256) void seq_valu(
    const float* __restrict__ A, const float* __restrict__ eps,
    const float* __restrict__ z0, const float* __restrict__ h0, const float* __restrict__ c0,
    const float* __restrict__ Wih, const float* __restrict__ Whh,
    const float* __restrict__ bih, const float* __restrict__ bhh,
    const float* __restrict__ W1, const float* __restrict__ b1,
    const float* __restrict__ W2, const float* __restrict__ b2,
    const float* __restrict__ Wz, const float* __restrict__ bz, float* __restrict__ out)
{
    __shared__ SM sm;
    const int tid = threadIdx.x;
    const int n0  = blockIdx.x * 4;
    if (tid < 128) { int rr = tid >> 5, cc = tid & 31; sm.zx[rr][8 + cc] = z0[cc]; }
    for (int i = tid; i < 4 * 256; i += 256) sm.h[i >> 8][i & 255] = h0[i & 255];
    float c[4];
    #pragma unroll
    for (int rr = 0; rr < 4; ++rr) c[rr] = c0[tid];
    float gbias[4];
    #pragma unroll
    for (int g = 0; g < 4; ++g) gbias[g] = bih[g * 256 + tid] + bhh[g * 256 + tid];

    for (int t = 0; t < T_LEN; ++t) {
        if (tid < 32) { int rr = tid >> 3, cc = tid & 7;
            sm.zx[rr][cc] = A[((size_t)(n0 + rr) * T_LEN + t) * 8 + cc]; }
        __syncthreads();
        float acc[4][4];
        #pragma unroll
        for (int g = 0; g < 4; ++g)
            #pragma unroll
            for (int rr = 0; rr < 4; ++rr) acc[g][rr] = gbias[g];
        for (int k = 0; k < 40; ++k) {
            float xv[4];
            #pragma unroll
            for (int rr = 0; rr < 4; ++rr) xv[rr] = sm.zx[rr][k];
            #pragma unroll
            for (int g = 0; g < 4; ++g) {
                float w = Wih[(size_t)(g * 256 + tid) * 40 + k];
                #pragma unroll
                for (int rr = 0; rr < 4; ++rr) acc[g][rr] += w * xv[rr];
            }
        }
        for (int k = 0; k < 256; ++k) {
            float hv[4];
            #pragma unroll
            for (int rr = 0; rr < 4; ++rr) hv[rr] = sm.h[rr][k];
            #pragma unroll
            for (int g = 0; g < 4; ++g) {
                float w = Whh[(size_t)(g * 256 + tid) * 256 + k];
                #pragma unroll
                for (int rr = 0; rr < 4; ++rr) acc[g][rr] += w * hv[rr];
            }
        }
        __syncthreads();
        #pragma unroll
        for (int rr = 0; rr < 4; ++rr) {
            float iv = 1.0f / (1.0f + expf(-acc[0][rr]));
            float fv = 1.0f / (1.0f + expf(-acc[1][rr]));
            float gv = tanhf(acc[2][rr]);
            float ov = 1.0f / (1.0f + expf(-acc[3][rr]));
            float cn = fv * c[rr] + iv * gv;
            c[rr] = cn;
            sm.h[rr][tid] = ov * tanhf(cn);
        }
        __syncthreads();
        { int col = tid & 127, rb = (tid >> 7) * 2;
          float a0 = b1[col], a1 = a0;
          for (int k = 0; k < 256; ++k) { float w = W1[(size_t)col * 256 + k];
              a0 += w * sm.h[rb][k]; a1 += w * sm.h[rb + 1][k]; }
          sm.u1[rb][col] = fmaxf(a0, 0.0f); sm.u1[rb + 1][col] = fmaxf(a1, 0.0f); }
        __syncthreads();
        { int col = tid & 127, rb = (tid >> 7) * 2;
          float a0 = b2[col], a1 = a0;
          for (int k = 0; k < 128; ++k) { float w = W2[(size_t)col * 128 + k];
              a0 += w * sm.u1[rb][k]; a1 += w * sm.u1[rb + 1][k]; }
          sm.u2[rb][col] = fmaxf(a0, 0.0f); sm.u2[rb + 1][col] = fmaxf(a1, 0.0f); }
        __syncthreads();
        { int rr = tid >> 6, col = tid & 63;
          float a0 = bz[col];
          for (int k = 0; k < 128; ++k) a0 += Wz[(size_t)col * 128 + k] * sm.u2[rr][k];
          sm.zz[rr][col] = a0; }
        __syncthreads();
        if (tid < 128) {
            int rr = tid >> 5, cc = tid & 31;
            float loc = sm.zz[rr][cc], raw = sm.zz[rr][cc + 32];
            float sp  = (raw > 20.0f) ? raw : log1pf(expf(raw));
            float ev  = eps[((size_t)(n0 + rr) * T_LEN + t) * 32 + cc];
            float zv  = loc + sp * ev;
            sm.zx[rr][8 + cc] = zv;
            out[((size_t)(n0 + rr) * T_LEN + t) * 32 + cc] = zv;
        }
        __syncthreads();
    }
}

extern "C" void kernel_launch(void* const* d_in, const int* in_sizes, int n_in,
                              void* d_out, int out_size, void* d_ws, size_t ws_size,
                              hipStream_t stream)
{
    const float* A   = (const float*)d_in[0];
    const float* eps = (const float*)d_in[1];
    const float* z0  = (const float*)d_in[2];
    const float* h0  = (const float*)d_in[3];
    const float* c0  = (const float*)d_in[4];
    const float* Wih = (const float*)d_in[5];
    const float* Whh = (const float*)d_in[6];
    const float* bih = (const float*)d_in[7];
    const float* bhh = (const float*)d_in[8];
    const float* W1  = (const float*)d_in[9];
    const float* b1  = (const float*)d_in[10];
    const float* W2  = (const float*)d_in[11];
    const float* b2  = (const float*)d_in[12];
    const float* Wz  = (const float*)d_in[13];
    const float* bz  = (const float*)d_in[14];
    float* out = (float*)d_out;

    if (ws_size >= WS_NEEDED) {
        prep_kernel<<<188, 256, 0, stream>>>(Wih, Whh, W1, W2, Wz, (unsigned char*)d_ws);
        seq_mfma<<<64, 1024, 0, stream>>>(A, eps, z0, h0, c0,
                                          bih, bhh, b1, b2, bz,
                                          (const unsigned char*)d_ws, out);
    } else {
        seq_valu<<<256, 256, 0, stream>>>(A, eps, z0, h0, c0, Wih, Whh, bih, bhh,
                                          W1, b1, W2, b2, Wz, bz, out);
    }
}

// Round 8
// 2187.132 us; speedup vs baseline: 1.1866x; 1.1866x over previous
//
#include <hip/hip_runtime.h>
#include <hip/hip_bf16.h>
#include <math.h>

typedef __bf16 bf16x8 __attribute__((ext_vector_type(8)));
typedef float floatx4 __attribute__((ext_vector_type(4)));

#define T_LEN 128

// ws layout: bf16 fragment-packed weights (unchanged from R5-R7)
#define WP_OFF   0
#define WP_SZ    (64*10*64*16)     // gates: 64 ct x 10 ki x 64 lanes x 16B = 655360
#define W1P_OFF  (WP_OFF + WP_SZ)
#define W1P_SZ   (8*8*64*16)       // 65536
#define W2P_OFF  (W1P_OFF + W1P_SZ)
#define W2P_SZ   (8*4*64*16)       // 32768
#define WZP_OFF  (W2P_OFF + W2P_SZ)
#define WZP_SZ   (4*4*64*16)       // 16384
#define WS_NEEDED ((size_t)(WZP_OFF + WZP_SZ))   // 770048 B

// s_waitcnt imm: wait until <=N vmem outstanding (expcnt/lgkmcnt = don't care)
#define WAITVM(N) (((N) & 0xF) | (0x7 << 4) | (0xF << 8) | (((N) >> 4) << 14))

// async 16B/lane global->LDS DMA; lds base is wave-uniform, data lands at
// ldsbase + lane*16 — exactly our fragment-linear packing.
__device__ __forceinline__ void dma16(const void* g, void* lds) {
    __builtin_amdgcn_global_load_lds(
        (const __attribute__((address_space(1))) void*)g,
        (__attribute__((address_space(3))) void*)lds,
        16, 0, 0);
}

// ---------------- prep: f32 weights -> bf16 B-fragment-linear in ws -------
__global__ void prep_kernel(const float* __restrict__ Wih, const float* __restrict__ Whh,
                            const float* __restrict__ W1,  const float* __restrict__ W2,
                            const float* __restrict__ Wz,  unsigned char* __restrict__ ws)
{
    int id = blockIdx.x * blockDim.x + threadIdx.x;
    __bf16* Wp  = (__bf16*)(ws + WP_OFF);
    __bf16* W1p = (__bf16*)(ws + W1P_OFF);
    __bf16* W2p = (__bf16*)(ws + W2P_OFF);
    __bf16* Wzp = (__bf16*)(ws + WZP_OFF);
    if (id < 40960) {                       // gates: 64 ct x 10 ki x 64 lanes
        int rem = id % 640, lane = rem % 64;
        int row = (id / 640) * 16 + (lane & 15);         // gate-output col
        int kb  = (rem / 64) * 32 + (lane >> 4) * 8;
        for (int j = 0; j < 8; ++j) {
            int k = kb + j;
            float v;
            if (k < 40)       v = Wih[row * 40 + k];
            else if (k < 296) v = Whh[row * 256 + (k - 40)];
            else              v = 0.0f;                   // K-pad 296..319
            Wp[(size_t)id * 8 + j] = (__bf16)v;
        }
    } else if (id < 45056) {                // W1: 8 ct x 8 ki
        int id2 = id - 40960;
        int rem = id2 % 512, lane = rem % 64;
        int row = (id2 / 512) * 16 + (lane & 15);
        int kb  = (rem / 64) * 32 + (lane >> 4) * 8;
        for (int j = 0; j < 8; ++j) W1p[(size_t)id2 * 8 + j] = (__bf16)W1[row * 256 + kb + j];
    } else if (id < 47104) {                // W2: 8 ct x 4 ki
        int id3 = id - 45056;
        int rem = id3 % 256, lane = rem % 64;
        int row = (id3 / 256) * 16 + (lane & 15);
        int kb  = (rem / 64) * 32 + (lane >> 4) * 8;
        for (int j = 0; j < 8; ++j) W2p[(size_t)id3 * 8 + j] = (__bf16)W2[row * 128 + kb + j];
    } else if (id < 48128) {                // Wz: 4 ct x 4 ki
        int id4 = id - 47104;
        int rem = id4 % 256, lane = rem % 64;
        int row = (id4 / 256) * 16 + (lane & 15);
        int kb  = (rem / 64) * 32 + (lane >> 4) * 8;
        for (int j = 0; j < 8; ++j) Wzp[(size_t)id4 * 8 + j] = (__bf16)Wz[row * 128 + kb + j];
    }
}

// ---------------- fast path: 64 blocks x 1024 threads, 16 rows/block ------
// All weights stream global->LDS via async DMA into per-wave double-buffered
// slots (zero VGPR cost in flight). Gates: explicit vmcnt(4) pipeline, no
// barriers (slots wave-private). MLP slabs DMA'd during preceding phase,
// drained by the existing stage barriers.
__global__ __launch_bounds__(1024) void seq_mfma(
    const float* __restrict__ A,   const float* __restrict__ eps,
    const float* __restrict__ z0,  const float* __restrict__ h0,
    const float* __restrict__ c0,
    const float* __restrict__ bih, const float* __restrict__ bhh,
    const float* __restrict__ b1,  const float* __restrict__ b2,
    const float* __restrict__ bz,
    const unsigned char* __restrict__ ws, float* __restrict__ out)
{
    const int tid  = threadIdx.x;
    const int wave = tid >> 6;
    const int lane = tid & 63;
    const int lrow = lane & 15;
    const int quad = lane >> 4;
    const int n0   = blockIdx.x * 16;

    __shared__ __align__(16) __bf16 slots[16][2][2048];  // per-wave 2 x 4KB slabs
    __shared__ __align__(16) __bf16 xh[16][328];   // [a(8)|z(32)|h(256)|pad(24)]
    __shared__ __align__(16) __bf16 u1s[16][136];
    __shared__ __align__(16) __bf16 u2s[16][136];
    __shared__ __align__(16) float  zzs[16][68];

    // per-lane global fragment pointers (include lane*16)
    const char* gbase[4];
    #pragma unroll
    for (int g = 0; g < 4; ++g)
        gbase[g] = (const char*)ws + WP_OFF + ((size_t)((g * 16 + wave) * 10) * 64 + lane) * 16;
    const char* u1base = (const char*)ws + W1P_OFF + ((size_t)((wave & 7) * 8) * 64 + lane) * 16;
    const char* u2base = (const char*)ws + W2P_OFF + ((size_t)((wave & 7) * 4) * 64 + lane) * 16;
    const char* uzbase = (const char*)ws + WZP_OFF + ((size_t)((wave & 3) * 4) * 64 + lane) * 16;

    const int unit = wave * 16 + lrow;
    float gb[4];
    #pragma unroll
    for (int g = 0; g < 4; ++g)
        gb[g] = bih[g * 256 + unit] + bhh[g * 256 + unit];
    float u1b = b1[(wave & 7) * 16 + lrow];
    float u2b = b2[(wave & 7) * 16 + lrow];
    float zzb = bz[(wave & 3) * 16 + lrow];

    float cst[4];
    {
        float cv = c0[unit];
        #pragma unroll
        for (int r = 0; r < 4; ++r) cst[r] = cv;
    }

    // init z/h/pad of xh
    for (int idx = tid; idx < 16 * 320; idx += 1024) {
        int r = idx / 320, col = 8 + idx % 320;
        float v;
        if (col < 40)       v = z0[col - 8];
        else if (col < 296) v = h0[col - 40];
        else                v = 0.0f;
        xh[r][col] = (__bf16)v;
    }

    // prefetch a(t=0)
    float a_cur = 0.0f;
    if (tid < 128)
        a_cur = A[((size_t)(n0 + (tid >> 3)) * T_LEN + 0) * 8 + (tid & 7)];

    for (int t = 0; t < T_LEN; ++t) {
        // ---- stage a_t from prefetch register
        if (tid < 128)
            xh[tid >> 3][tid & 7] = (__bf16)a_cur;
        __syncthreads();   // orders a-stage, prev z writes, init; drains all DMA

        // ---- plain prefetches (oldest in vmcnt queue — retire first)
        float eps_cur = 0.0f;
        if (tid < 512)
            eps_cur = eps[((size_t)(n0 + (tid >> 5)) * T_LEN + t) * 32 + (tid & 31)];
        float a_nxt = 0.0f;
        if (t + 1 < T_LEN && tid < 128)
            a_nxt = A[((size_t)(n0 + (tid >> 3)) * T_LEN + (t + 1)) * 8 + (tid & 7)];

        // ---- kick the gates DMA pipeline: slabs ki=0,1
        #pragma unroll
        for (int g = 0; g < 4; ++g)
            dma16(gbase[g], &slots[wave][0][g * 512]);
        #pragma unroll
        for (int g = 0; g < 4; ++g)
            dma16(gbase[g] + 1024, &slots[wave][1][g * 512]);

        // ---- gates: consume slab ki, refill slab ki+2 (same slot), vmcnt(4)
        floatx4 acc[4];
        #pragma unroll
        for (int g = 0; g < 4; ++g)
            acc[g] = (floatx4){gb[g], gb[g], gb[g], gb[g]};

        #pragma unroll
        for (int ki = 0; ki < 10; ++ki) {
            const int s = ki & 1;
            __builtin_amdgcn_s_waitcnt(WAITVM(4));   // slab ki landed (only ki+1 newer)
            __builtin_amdgcn_sched_barrier(0);
            bf16x8 a = *(const bf16x8*)&xh[lrow][ki * 32 + quad * 8];
            #pragma unroll
            for (int g = 0; g < 4; ++g) {
                bf16x8 b = *(const bf16x8*)&slots[wave][s][g * 512 + lane * 8];
                acc[g] = __builtin_amdgcn_mfma_f32_16x16x32_bf16(a, b, acc[g], 0, 0, 0);
            }
            __builtin_amdgcn_sched_barrier(0);       // reads before slot overwrite
            if (ki + 2 < 10) {
                #pragma unroll
                for (int g = 0; g < 4; ++g)
                    dma16(gbase[g] + (ki + 2) * 1024, &slots[wave][s][g * 512]);
            } else if (ki == 8) {                    // slot 0 free -> u1 frags 0..3
                if (wave < 8) {
                    #pragma unroll
                    for (int f = 0; f < 4; ++f)
                        dma16(u1base + f * 1024, &slots[wave][0][f * 512]);
                }
            } else {                                 // ki==9, slot 1 -> u1 frags 4..7
                if (wave < 8) {
                    #pragma unroll
                    for (int f = 0; f < 4; ++f)
                        dma16(u1base + (4 + f) * 1024, &slots[wave][1][f * 512]);
                }
            }
        }
        __syncthreads();   // xh reads complete; drains u1 slabs into LDS

        // ---- LSTM cell: acc[0..3] = i,f,g,o for (row=quad*4+r, col=unit)
        #pragma unroll
        for (int r = 0; r < 4; ++r) {
            float iv = 1.0f / (1.0f + expf(-acc[0][r]));
            float fv = 1.0f / (1.0f + expf(-acc[1][r]));
            float gv = tanhf(acc[2][r]);
            float ov = 1.0f / (1.0f + expf(-acc[3][r]));
            float cn = fv * cst[r] + iv * gv;
            cst[r] = cn;
            xh[quad * 4 + r][40 + unit] = (__bf16)(ov * tanhf(cn));
        }
        __syncthreads();

        // ---- u1 = relu(h @ W1^T + b1): waves 0..7, weights from slots
        if (wave < 8) {
            floatx4 a1 = (floatx4){u1b, u1b, u1b, u1b};
            #pragma unroll
            for (int ki = 0; ki < 8; ++ki) {
                bf16x8 a = *(const bf16x8*)&xh[lrow][40 + ki * 32 + quad * 8];
                bf16x8 b = *(const bf16x8*)&slots[wave][ki >> 2][(ki & 3) * 512 + lane * 8];
                a1 = __builtin_amdgcn_mfma_f32_16x16x32_bf16(a, b, a1, 0, 0, 0);
            }
            #pragma unroll
            for (int r = 0; r < 4; ++r)
                u1s[quad * 4 + r][wave * 16 + lrow] = (__bf16)fmaxf(a1[r], 0.0f);
            __builtin_amdgcn_sched_barrier(0);
            #pragma unroll
            for (int f = 0; f < 4; ++f)          // u2 slab -> slot 0
                dma16(u2base + f * 1024, &slots[wave][0][f * 512]);
        }
        __syncthreads();   // u1s ready; u2 slab drained

        // ---- u2 = relu(u1 @ W2^T + b2): waves 0..7
        if (wave < 8) {
            floatx4 a2 = (floatx4){u2b, u2b, u2b, u2b};
            #pragma unroll
            for (int ki = 0; ki < 4; ++ki) {
                bf16x8 a = *(const bf16x8*)&u1s[lrow][ki * 32 + quad * 8];
                bf16x8 b = *(const bf16x8*)&slots[wave][0][ki * 512 + lane * 8];
                a2 = __builtin_amdgcn_mfma_f32_16x16x32_bf16(a, b, a2, 0, 0, 0);
            }
            #pragma unroll
            for (int r = 0; r < 4; ++r)
                u2s[quad * 4 + r][wave * 16 + lrow] = (__bf16)fmaxf(a2[r], 0.0f);
        }
        if (wave < 4) {
            __builtin_amdgcn_sched_barrier(0);
            #pragma unroll
            for (int f = 0; f < 4; ++f)          // wz slab -> slot 1
                dma16(uzbase + f * 1024, &slots[wave][1][f * 512]);
        }
        __syncthreads();   // u2s ready; wz slab drained

        // ---- zz = u2 @ Wz^T + bz: waves 0..3
        if (wave < 4) {
            floatx4 a3 = (floatx4){zzb, zzb, zzb, zzb};
            #pragma unroll
            for (int ki = 0; ki < 4; ++ki) {
                bf16x8 a = *(const bf16x8*)&u2s[lrow][ki * 32 + quad * 8];
                bf16x8 b = *(const bf16x8*)&slots[wave][1][ki * 512 + lane * 8];
                a3 = __builtin_amdgcn_mfma_f32_16x16x32_bf16(a, b, a3, 0, 0, 0);
            }
            #pragma unroll
            for (int r = 0; r < 4; ++r)
                zzs[quad * 4 + r][wave * 16 + lrow] = a3[r];
        }
        __syncthreads();

        // ---- z = loc + softplus(raw)*eps (prefetched); f32 out + bf16 feedback
        if (tid < 512) {
            int r = tid >> 5, c = tid & 31;
            float loc = zzs[r][c];
            float raw = zzs[r][c + 32];
            float sp  = (raw > 20.0f) ? raw : log1pf(expf(raw));
            float zv  = loc + sp * eps_cur;
            xh[r][8 + c] = (__bf16)zv;
            out[((size_t)(n0 + r) * T_LEN + t) * 32 + c] = zv;
        }
        a_cur = a_nxt;
        // z writes (cols 8..39) vs next a-stage (cols 0..7) disjoint;
        // next post-a-stage barrier orders z before gates reads.
    }
}

// ---------------- fallback: proven R4 VALU kernel (f32 hard-coded) --------
struct SM {
    float zx[4][40]; float h[4][256]; float u1[4][128]; float u2[4][128]; float zz[4][64];
};

__global__ __launch_bounds__(256) void seq_valu(
    const float* __restrict__ A, const float* __restrict__ eps,
    const float* __restrict__ z0, const float* __restrict__ h0, const float* __restrict__ c0,
    const float* __restrict__ Wih, const float* __restrict__ Whh,
    const float* __restrict__ bih, const float* __restrict__ bhh,
    const float* __restrict__ W1, const float* __restrict__ b1,
    const float* __restrict__ W2, const float* __restrict__ b2,
    const float* __restrict__ Wz, const float* __restrict__ bz, float* __restrict__ out)
{
    __shared__ SM sm;
    const int tid = threadIdx.x;
    const int n0  = blockIdx.x * 4;
    if (tid < 128) { int rr = tid >> 5, cc = tid & 31; sm.zx[rr][8 + cc] = z0[cc]; }
    for (int i = tid; i < 4 * 256; i += 256) sm.h[i >> 8][i & 255] = h0[i & 255];
    float c[4];
    #pragma unroll
    for (int rr = 0; rr < 4; ++rr) c[rr] = c0[tid];
    float gbias[4];
    #pragma unroll
    for (int g = 0; g < 4; ++g) gbias[g] = bih[g * 256 + tid] + bhh[g * 256 + tid];

    for (int t = 0; t < T_LEN; ++t) {
        if (tid < 32) { int rr = tid >> 3, cc = tid & 7;
            sm.zx[rr][cc] = A[((size_t)(n0 + rr) * T_LEN + t) * 8 + cc]; }
        __syncthreads();
        float acc[4][4];
        #pragma unroll
        for (int g = 0; g < 4; ++g)
            #pragma unroll
            for (int rr = 0; rr < 4; ++rr) acc[g][rr] = gbias[g];
        for (int k = 0; k < 40; ++k) {
            float xv[4];
            #pragma unroll
            for (int rr = 0; rr < 4; ++rr) xv[rr] = sm.zx[rr][k];
            #pragma unroll
            for (int g = 0; g < 4; ++g) {
                float w = Wih[(size_t)(g * 256 + tid) * 40 + k];
                #pragma unroll
                for (int rr = 0; rr < 4; ++rr) acc[g][rr] += w * xv[rr];
            }
        }
        for (int k = 0; k < 256; ++k) {
            float hv[4];
            #pragma unroll
            for (int rr = 0; rr < 4; ++rr) hv[rr] = sm.h[rr][k];
            #pragma unroll
            for (int g = 0; g < 4; ++g) {
                float w = Whh[(size_t)(g * 256 + tid) * 256 + k];
                #pragma unroll
                for (int rr = 0; rr < 4; ++rr) acc[g][rr] += w * hv[rr];
            }
        }
        __syncthreads();
        #pragma unroll
        for (int rr = 0; rr < 4; ++rr) {
            float iv = 1.0f / (1.0f + expf(-acc[0][rr]));
            float fv = 1.0f / (1.0f + expf(-acc[1][rr]));
            float gv = tanhf(acc[2][rr]);
            float ov = 1.0f / (1.0f + expf(-acc[3][rr]));
            float cn = fv * c[rr] + iv * gv;
            c[rr] = cn;
            sm.h[rr][tid] = ov * tanhf(cn);
        }
        __syncthreads();
        { int col = tid & 127, rb = (tid >> 7) * 2;
          float a0 = b1[col], a1 = a0;
          for (int k = 0; k < 256; ++k) { float w = W1[(size_t)col * 256 + k];
              a0 += w * sm.h[rb][k]; a1 += w * sm.h[rb + 1][k]; }
          sm.u1[rb][col] = fmaxf(a0, 0.0f); sm.u1[rb + 1][col] = fmaxf(a1, 0.0f); }
        __syncthreads();
        { int col = tid & 127, rb = (tid >> 7) * 2;
          float a0 = b2[col], a1 = a0;
          for (int k = 0; k < 128; ++k) { float w = W2[(size_t)col * 128 + k];
              a0 += w * sm.u1[rb][k]; a1 += w * sm.u1[rb + 1][k]; }
          sm.u2[rb][col] = fmaxf(a0, 0.0f); sm.u2[rb + 1][col] = fmaxf(a1, 0.0f); }
        __syncthreads();
        { int rr = tid >> 6, col = tid & 63;
          float a0 = bz[col];
          for (int k = 0; k < 128; ++k) a0 += Wz[(size_t)col * 128 + k] * sm.u2[rr][k];
          sm.zz[rr][col] = a0; }
        __syncthreads();
        if (tid < 128) {
            int rr = tid >> 5, cc = tid & 31;
            float loc = sm.zz[rr][cc], raw = sm.zz[rr][cc + 32];
            float sp  = (raw > 20.0f) ? raw : log1pf(expf(raw));
            float ev  = eps[((size_t)(n0 + rr) * T_LEN + t) * 32 + cc];
            float zv  = loc + sp * ev;
            sm.zx[rr][8 + cc] = zv;
            out[((size_t)(n0 + rr) * T_LEN + t) * 32 + cc] = zv;
        }
        __syncthreads();
    }
}

extern "C" void kernel_launch(void* const* d_in, const int* in_sizes, int n_in,
                              void* d_out, int out_size, void* d_ws, size_t ws_size,
                              hipStream_t stream)
{
    const float* A   = (const float*)d_in[0];
    const float* eps = (const float*)d_in[1];
    const float* z0  = (const float*)d_in[2];
    const float* h0  = (const float*)d_in[3];
    const float* c0  = (const float*)d_in[4];
    const float* Wih = (const float*)d_in[5];
    const float* Whh = (const float*)d_in[6];
    const float* bih = (const float*)d_in[7];
    const float* bhh = (const float*)d_in[8];
    const float* W1  = (const float*)d_in[9];
    const float* b1  = (const float*)d_in[10];
    const float* W2  = (const float*)d_in[11];
    const float* b2  = (const float*)d_in[12];
    const float* Wz  = (const float*)d_in[13];
    const float* bz  = (const float*)d_in[14];
    float* out = (float*)d_out;

    if (ws_size >= WS_NEEDED) {
        prep_kernel<<<188, 256, 0, stream>>>(Wih, Whh, W1, W2, Wz, (unsigned char*)d_ws);
        seq_mfma<<<64, 1024, 0, stream>>>(A, eps, z0, h0, c0,
                                          bih, bhh, b1, b2, bz,
                                          (const unsigned char*)d_ws, out);
    } else {
        seq_valu<<<256, 256, 0, stream>>>(A, eps, z0, h0, c0, Wih, Whh, bih, bhh,
                                          W1, b1, W2, b2, Wz, bz, out);
    }
}